// Round 6
// baseline (169.165 us; speedup 1.0000x reference)
//
#include <hip/hip_runtime.h>
#include <hip/hip_bf16.h>

#define NTAGS 64
#define START_TAG 1
#define END_TAG 63
#define LN2F 0.69314718055994530942f
#define LDSP 68  // padded row stride (floats) for the 16x64 P buffer

typedef float v4f __attribute__((ext_vector_type(4)));
typedef short s16x8 __attribute__((ext_vector_type(8)));

static __device__ __forceinline__ short f2bf(float x) {
    union { __hip_bfloat16 h; short s; } u;
    u.h = __float2bfloat16(x);
    return u.s;
}
template <int PAT>
static __device__ __forceinline__ float swz(float x) {
    return __int_as_float(__builtin_amdgcn_ds_swizzle(__float_as_int(x), PAT));
}

// ---------------------------------------------------------------------------
// One wave advances 16 batches simultaneously.
// fwd:  P' = (P @ expT) ∘ E_t            (per masked step)
// bwd:  W' = ((W ∘ E_t) @ expT^T)
// MFMA 16x16x32 bf16: A = P (M=batch16, K=tag), B = expT (or expT^T), 4 N-tiles
// x 2 K-chunks = 8 MFMA/step. C layout: col=lane&15, row=4*(lane>>4)+reg.
// A layout: row=lane&15, k=8*(lane>>4)+e. C->A transpose via one LDS round
// trip: 16 ds_write_b32 (scattered, stride-68 rows -> <=2-way free) +
// 4 ds_read_b128. Per-batch power-of-2 rescale every 8 steps.
// ---------------------------------------------------------------------------
template <bool FWD>
static __device__ __forceinline__ void run_chain(const float* __restrict__ feats,
                                                 const float* __restrict__ mask,
                                                 const float* __restrict__ trans,
                                                 float* __restrict__ outv,
                                                 int* __restrict__ oute,
                                                 int S, int H, int b0, float* sP) {
    const int lane = threadIdx.x;
    const int c = lane & 15, g = lane >> 4;

    // B fragments (resident): Bf[n][kk], element e = B[32kk+8g+e][16n+c]
    // fwd: B[k][j] = expT[k][j]   -> trans[(32kk+8g+e)*64 + 16n+c]
    // bwd: B[k][i] = expT[i][k]   -> trans[(16n+c)*64 + 32kk+8g+e]
    s16x8 Bf[4][2];
#pragma unroll
    for (int n = 0; n < 4; ++n)
#pragma unroll
        for (int kk = 0; kk < 2; ++kk)
#pragma unroll
            for (int e = 0; e < 8; ++e) {
                float tv = FWD ? trans[(32 * kk + 8 * g + e) * NTAGS + 16 * n + c]
                               : trans[(16 * n + c) * NTAGS + 32 * kk + 8 * g + e];
                Bf[n][kk][e] = f2bf(__expf(tv));
            }

    // state: p[n][r] = P[batch 4g+r][tag 16n+c]
    v4f p[4];
#pragma unroll
    for (int n = 0; n < 4; ++n) {
        float iv = FWD ? ((16 * n + c == START_TAG) ? 1.0f : 0.0f)
                       : __expf(trans[(16 * n + c) * NTAGS + END_TAG]);
        p[n] = (v4f){iv, iv, iv, iv};
    }
    int es0 = 0, es1 = 0, es2 = 0, es3 = 0;

    const int NS = FWD ? H : (S - H);

    // emission/mask prefetch buffers: 2 pair-buffers (2 steps each)
    float E0a[16], E0b[16], E1a[16], E1b[16];
    float M0a[4], M0b[4], M1a[4], M1b[4];

#define TIDX(s) (FWD ? (s) : (S - 1 - (s)))
#define LOADEM(s, E, M)                                                              \
    do {                                                                             \
        const int tt_ = TIDX(s);                                                     \
        _Pragma("unroll") for (int n = 0; n < 4; ++n)                                \
            _Pragma("unroll") for (int r = 0; r < 4; ++r)                            \
                E[n * 4 + r] =                                                       \
                    feats[((size_t)(b0 + 4 * g + r) * S + tt_) * NTAGS + 16 * n + c];\
        _Pragma("unroll") for (int r = 0; r < 4; ++r)                                \
            M[r] = mask[(size_t)(b0 + 4 * g + r) * S + tt_];                         \
    } while (0)

#define STEP(E, M)                                                                   \
    do {                                                                             \
        float X[16];                                                                 \
        _Pragma("unroll") for (int i = 0; i < 16; ++i) X[i] = __expf(E[i]);          \
        _Pragma("unroll") for (int n = 0; n < 4; ++n)                                \
            _Pragma("unroll") for (int r = 0; r < 4; ++r) {                          \
                float wvv = FWD ? p[n][r] : p[n][r] * X[n * 4 + r];                  \
                sP[(4 * g + r) * LDSP + 16 * n + c] = wvv;                           \
            }                                                                        \
        s16x8 a0, a1;                                                                \
        {                                                                            \
            v4f qa = *(const v4f*)(sP + c * LDSP + 8 * g);                           \
            v4f qb = *(const v4f*)(sP + c * LDSP + 8 * g + 4);                       \
            v4f qc = *(const v4f*)(sP + c * LDSP + 8 * g + 32);                      \
            v4f qd = *(const v4f*)(sP + c * LDSP + 8 * g + 36);                      \
            a0[0] = f2bf(qa.x); a0[1] = f2bf(qa.y); a0[2] = f2bf(qa.z);              \
            a0[3] = f2bf(qa.w); a0[4] = f2bf(qb.x); a0[5] = f2bf(qb.y);              \
            a0[6] = f2bf(qb.z); a0[7] = f2bf(qb.w);                                  \
            a1[0] = f2bf(qc.x); a1[1] = f2bf(qc.y); a1[2] = f2bf(qc.z);              \
            a1[3] = f2bf(qc.w); a1[4] = f2bf(qd.x); a1[5] = f2bf(qd.y);              \
            a1[6] = f2bf(qd.z); a1[7] = f2bf(qd.w);                                  \
        }                                                                            \
        v4f acc[4];                                                                  \
        _Pragma("unroll") for (int n = 0; n < 4; ++n) {                              \
            v4f z = {0.f, 0.f, 0.f, 0.f};                                            \
            acc[n] = __builtin_amdgcn_mfma_f32_16x16x32_bf16(a0, Bf[n][0], z, 0, 0, 0); \
            acc[n] = __builtin_amdgcn_mfma_f32_16x16x32_bf16(a1, Bf[n][1], acc[n], 0, 0, 0); \
        }                                                                            \
        _Pragma("unroll") for (int n = 0; n < 4; ++n)                                \
            _Pragma("unroll") for (int r = 0; r < 4; ++r) {                          \
                float nv = FWD ? acc[n][r] * X[n * 4 + r] : acc[n][r];               \
                p[n][r] = (M[r] != 0.0f) ? nv : p[n][r];                             \
            }                                                                        \
    } while (0)

#define RESCALE_R(r, esr)                                                            \
    do {                                                                             \
        float m_ = fmaxf(fmaxf(p[0][r], p[1][r]), fmaxf(p[2][r], p[3][r]));          \
        m_ = fmaxf(m_, swz<0x041F>(m_));                                             \
        m_ = fmaxf(m_, swz<0x081F>(m_));                                             \
        m_ = fmaxf(m_, swz<0x101F>(m_));                                             \
        m_ = fmaxf(m_, swz<0x201F>(m_));                                             \
        int ex_;                                                                     \
        (void)frexpf(m_, &ex_);                                                      \
        _Pragma("unroll") for (int n = 0; n < 4; ++n)                                \
            p[n][r] = ldexpf(p[n][r], -ex_);                                         \
        esr += ex_;                                                                  \
    } while (0)

    LOADEM(0, E0a, M0a);
    LOADEM(1, E0b, M0b);

    for (int s = 0; s < NS; s += 4) {
        if (s + 2 < NS) { LOADEM(s + 2, E1a, M1a); LOADEM(s + 3, E1b, M1b); }
        STEP(E0a, M0a);
        STEP(E0b, M0b);
        if (s + 4 < NS) { LOADEM(s + 4, E0a, M0a); LOADEM(s + 5, E0b, M0b); }
        STEP(E1a, M1a);
        STEP(E1b, M1b);
        if (((s + 4) & 7) == 0) {
            RESCALE_R(0, es0);
            RESCALE_R(1, es1);
            RESCALE_R(2, es2);
            RESCALE_R(3, es3);
        }
    }

    // write out state + exponents
#pragma unroll
    for (int n = 0; n < 4; ++n)
#pragma unroll
        for (int r = 0; r < 4; ++r)
            outv[(size_t)(b0 + 4 * g + r) * NTAGS + 16 * n + c] = p[n][r];
    if (c == 0) {
        oute[b0 + 4 * g + 0] = es0;
        oute[b0 + 4 * g + 1] = es1;
        oute[b0 + 4 * g + 2] = es2;
        oute[b0 + 4 * g + 3] = es3;
    }
#undef TIDX
#undef LOADEM
#undef STEP
#undef RESCALE_R
}

__global__ __launch_bounds__(64) void crf_chains(const float* __restrict__ feats,
                                                 const float* __restrict__ mask,
                                                 const int* __restrict__ tags,
                                                 const float* __restrict__ trans,
                                                 float* __restrict__ zv,
                                                 float* __restrict__ wv,
                                                 float* __restrict__ gs,
                                                 int* __restrict__ ez,
                                                 int* __restrict__ ew,
                                                 int S, int H, int B, int nw) {
    const int bid = (int)blockIdx.x;
    const int lane = threadIdx.x;

    if (bid >= 2 * nw) {
        // ---- gold path score: one wave per batch ----
        const int b = bid - 2 * nw;
        const float* fb = feats + (size_t)b * S * NTAGS;
        const float* mb = mask + (size_t)b * S;
        const int* tb = tags + (size_t)b * S;
        float acc = 0.f, msum = 0.f;
        for (int t = lane; t < S; t += 64) {
            int cur = tb[t];
            int prev = (t == 0) ? START_TAG : tb[t - 1];
            float m = mb[t];
            acc += (fb[t * NTAGS + cur] + trans[prev * NTAGS + cur]) * m;
            msum += m;
        }
#pragma unroll
        for (int sh = 32; sh >= 1; sh >>= 1) {
            acc += __shfl_xor(acc, sh);
            msum += __shfl_xor(msum, sh);
        }
        if (lane == 0) {
            int seq_end = (int)(msum + 0.5f) - 1;
            int last = (seq_end >= 0) ? tb[seq_end] : START_TAG;
            gs[b] = acc + trans[last * NTAGS + END_TAG];
        }
        return;
    }

    __shared__ __align__(16) float sP[16 * LDSP];
    if (bid < nw) {
        run_chain<true>(feats, mask, trans, zv, ez, S, H, bid * 16, sP);
    } else {
        run_chain<false>(feats, mask, trans, wv, ew, S, H, (bid - nw) * 16, sP);
    }
}

// ---------------------------------------------------------------------------
// combine + mean: out = mean_b( log(z_b . w_b) + (ez+ew)*ln2 - gs_b )
// ---------------------------------------------------------------------------
__global__ __launch_bounds__(1024) void crf_combine(const float* __restrict__ zv,
                                                    const float* __restrict__ wv,
                                                    const float* __restrict__ gs,
                                                    const int* __restrict__ ez,
                                                    const int* __restrict__ ew,
                                                    float* __restrict__ out, int B) {
    const int tid = threadIdx.x;
    const int wave = tid >> 6, lane = tid & 63;
    float local = 0.f;
    for (int b = wave; b < B; b += 16) {
        float s = zv[(size_t)b * NTAGS + lane] * wv[(size_t)b * NTAGS + lane];
#pragma unroll
        for (int sh = 32; sh >= 1; sh >>= 1) s += __shfl_xor(s, sh);
        if (lane == 0)
            local += logf(s) + (float)(ez[b] + ew[b]) * LN2F - gs[b];
    }
    __shared__ float buf[16];
    if (lane == 0) buf[wave] = local;
    __syncthreads();
    if (tid == 0) {
        float a = 0.f;
#pragma unroll
        for (int i = 0; i < 16; ++i) a += buf[i];
        out[0] = a / (float)B;
    }
}

extern "C" void kernel_launch(void* const* d_in, const int* in_sizes, int n_in,
                              void* d_out, int out_size, void* d_ws, size_t ws_size,
                              hipStream_t stream) {
    const float* feats = (const float*)d_in[0];
    const float* mask  = (const float*)d_in[1];
    const int*   tags  = (const int*)d_in[2];
    const float* trans = (const float*)d_in[3];
    float* out = (float*)d_out;

    const int S = 512;              // reference shape
    const int B = in_sizes[1] / S;  // mask is (B,S)
    const int H = S / 2;
    const int nw = B / 16;          // 16 batches per chain wave

    float* zv = (float*)d_ws;
    float* wv = zv + (size_t)B * NTAGS;
    float* gs = wv + (size_t)B * NTAGS;
    int* ez = (int*)(gs + B);
    int* ew = ez + B;

    crf_chains<<<2 * nw + B, 64, 0, stream>>>(feats, mask, tags, trans,
                                              zv, wv, gs, ez, ew, S, H, B, nw);
    crf_combine<<<1, 1024, 0, stream>>>(zv, wv, gs, ez, ew, out, B);
}

// Round 7
// 95.057 us; speedup vs baseline: 1.7796x; 1.7796x over previous
//
#include <hip/hip_runtime.h>

#define NTAGS 64
#define START_TAG 1
#define END_TAG 63
#define LN2F 0.69314718055994530942f

typedef float v2f __attribute__((ext_vector_type(2)));
typedef float v4f __attribute__((ext_vector_type(4)));

static __device__ __forceinline__ v2f pkfma(v2f a, v2f b, v2f c) {
    return __builtin_elementwise_fma(a, b, c);
}

// ---------------------------------------------------------------------------
// One wave = one chain (one batch, one direction).
// fwd:  p'[j] = (sum_i p[i] expT[i][j]) * E_t[j],   t = 0..H-1
// bwd:  w'[i] = sum_j expT[i][j] (E_t[j] w[j]),     t = S-1..H
// 2-way split dot: lane l reads only p[32h..32h+32) (8 uniform ds_read_b128,
// 2-way bank alias = free) and accumulates packed partials for outputs
// (l, l^32); one __shfl_xor(·,32) combines. 10 DS ops/step vs 17 for the
// full-broadcast version. Rescale: exact power-of-2 via readfirstlane proxy
// exponent every 4 steps (lane0 is within ~2^24 of max; no cross-lane max).
// ---------------------------------------------------------------------------
template <bool FWD>
static __device__ __forceinline__ void run_chain(const float* __restrict__ feats,
                                                 const float* __restrict__ mask,
                                                 const float* __restrict__ trans,
                                                 float* __restrict__ outv,
                                                 int* __restrict__ oute,
                                                 int S, int H, int b, float* pl) {
    const int lane = threadIdx.x;
    const int ibase = (lane >> 5) * 32;  // my half of the reduction range
    const int lx = lane ^ 32;

    // c2[i] = coeffs for outputs (lane, lane^32), reduction index ibase+i
    v2f c2[32];
#pragma unroll
    for (int i = 0; i < 32; ++i) {
        if (FWD) {
            c2[i].x = __expf(trans[(ibase + i) * NTAGS + lane]);
            c2[i].y = __expf(trans[(ibase + i) * NTAGS + lx]);
        } else {
            c2[i].x = __expf(trans[lane * NTAGS + (ibase + i)]);
            c2[i].y = __expf(trans[lx * NTAGS + (ibase + i)]);
        }
    }

    const float* fb = feats + (size_t)b * S * NTAGS;
    const float* mb = mask + (size_t)b * S;

    float p = FWD ? ((lane == START_TAG) ? 1.0f : 0.0f)
                  : __expf(trans[lane * NTAGS + END_TAG]);
    int esum = 0;
    const int NS = FWD ? H : (S - H);  // assumed %4==0 (S=512 reference)

#define TIDX(s) (FWD ? (s) : (S - 1 - (s)))

    float E[4], M[4];
    {
#pragma unroll
        for (int u = 0; u < 4; ++u) E[u] = __expf(fb[(size_t)TIDX(u) * NTAGS + lane]);
        if (FWD) {
            v4f v = *(const v4f*)(mb);
            M[0] = v.x; M[1] = v.y; M[2] = v.z; M[3] = v.w;
        } else {
            v4f v = *(const v4f*)(mb + S - 4);
            M[0] = v.w; M[1] = v.z; M[2] = v.y; M[3] = v.x;
        }
    }

#define STEP(Eu, Mu)                                                        \
    do {                                                                    \
        pl[lane] = FWD ? p : p * Eu; /* publish (in-order DS, same wave) */ \
        v4f q[8];                                                           \
        _Pragma("unroll") for (int r = 0; r < 8; ++r)                       \
            q[r] = ((const v4f*)(pl + ibase))[r];                           \
        v2f a0 = {0.f, 0.f}, a1 = a0, a2 = a0, a3 = a0;                     \
        _Pragma("unroll") for (int r = 0; r < 8; ++r) {                     \
            a0 = pkfma((v2f){q[r].x, q[r].x}, c2[4 * r + 0], a0);           \
            a1 = pkfma((v2f){q[r].y, q[r].y}, c2[4 * r + 1], a1);           \
            a2 = pkfma((v2f){q[r].z, q[r].z}, c2[4 * r + 2], a2);           \
            a3 = pkfma((v2f){q[r].w, q[r].w}, c2[4 * r + 3], a3);           \
        }                                                                   \
        v2f acc = (a0 + a1) + (a2 + a3);                                    \
        float partner = __shfl_xor(acc.y, 32);                              \
        float nv = acc.x + partner;                                         \
        float pn = FWD ? nv * Eu : nv;                                      \
        p = (Mu != 0.0f) ? pn : p;                                          \
    } while (0)

    for (int t0 = 0; t0 < NS; t0 += 4) {
        float En[4];
        v4f Mn;
        const bool more = (t0 + 4) < NS;
        if (more) {
#pragma unroll
            for (int u = 0; u < 4; ++u)
                En[u] = fb[(size_t)TIDX(t0 + 4 + u) * NTAGS + lane];
            Mn = FWD ? *(const v4f*)(mb + t0 + 4)
                     : *(const v4f*)(mb + S - 8 - t0);
        }

        STEP(E[0], M[0]);
        STEP(E[1], M[1]);
        STEP(E[2], M[2]);
        STEP(E[3], M[3]);

        // exact power-of-2 rescale via lane-0 proxy exponent (uniform).
        {
            int si = __builtin_amdgcn_readfirstlane(__float_as_int(p));
            int ef = (si >> 23) & 0xFF;
            if (ef != 0) {  // skip when lane0 is zero/denormal (one-hot start)
                int ex = ef - 127;
                p = ldexpf(p, -ex);
                esum += ex;
            }
        }

        if (more) {
#pragma unroll
            for (int u = 0; u < 4; ++u) E[u] = __expf(En[u]);
            if (FWD) { M[0] = Mn.x; M[1] = Mn.y; M[2] = Mn.z; M[3] = Mn.w; }
            else     { M[0] = Mn.w; M[1] = Mn.z; M[2] = Mn.y; M[3] = Mn.x; }
        }
    }
#undef STEP
#undef TIDX

    outv[(size_t)b * NTAGS + lane] = p;
    if (lane == 0) oute[b] = esum;
}

// ---------------------------------------------------------------------------
// blocks [0,B): forward halves; [B,2B): backward halves; [2B,3B): gold score
// ---------------------------------------------------------------------------
__global__ __launch_bounds__(64) void crf_chains(const float* __restrict__ feats,
                                                 const float* __restrict__ mask,
                                                 const int* __restrict__ tags,
                                                 const float* __restrict__ trans,
                                                 float* __restrict__ zv,
                                                 float* __restrict__ wv,
                                                 float* __restrict__ gs,
                                                 int* __restrict__ ez,
                                                 int* __restrict__ ew,
                                                 int S, int H, int B) {
    const int bid = (int)blockIdx.x;
    const int lane = threadIdx.x;

    if (bid >= 2 * B) {
        // ---- gold path score: one wave per batch ----
        const int b = bid - 2 * B;
        const float* fb = feats + (size_t)b * S * NTAGS;
        const float* mb = mask + (size_t)b * S;
        const int* tb = tags + (size_t)b * S;
        float acc = 0.f, msum = 0.f;
        for (int t = lane; t < S; t += 64) {
            int cur = tb[t];
            int prev = (t == 0) ? START_TAG : tb[t - 1];
            float m = mb[t];
            acc += (fb[t * NTAGS + cur] + trans[prev * NTAGS + cur]) * m;
            msum += m;
        }
#pragma unroll
        for (int sh = 32; sh >= 1; sh >>= 1) {
            acc += __shfl_xor(acc, sh);
            msum += __shfl_xor(msum, sh);
        }
        if (lane == 0) {
            int seq_end = (int)(msum + 0.5f) - 1;
            int last = (seq_end >= 0) ? tb[seq_end] : START_TAG;
            gs[b] = acc + trans[last * NTAGS + END_TAG];
        }
        return;
    }

    __shared__ __align__(16) float pl[NTAGS];
    if (bid < B) run_chain<true>(feats, mask, trans, zv, ez, S, H, bid, pl);
    else         run_chain<false>(feats, mask, trans, wv, ew, S, H, bid - B, pl);
}

// ---------------------------------------------------------------------------
// combine + mean: out = mean_b( log(z_b . w_b) + (ez+ew)*ln2 - gs_b )
// ---------------------------------------------------------------------------
__global__ __launch_bounds__(1024) void crf_combine(const float* __restrict__ zv,
                                                    const float* __restrict__ wv,
                                                    const float* __restrict__ gs,
                                                    const int* __restrict__ ez,
                                                    const int* __restrict__ ew,
                                                    float* __restrict__ out, int B) {
    const int tid = threadIdx.x;
    const int wave = tid >> 6, lane = tid & 63;
    float local = 0.f;
    for (int b = wave; b < B; b += 16) {
        float s = zv[(size_t)b * NTAGS + lane] * wv[(size_t)b * NTAGS + lane];
#pragma unroll
        for (int sh = 32; sh >= 1; sh >>= 1) s += __shfl_xor(s, sh);
        if (lane == 0)
            local += logf(s) + (float)(ez[b] + ew[b]) * LN2F - gs[b];
    }
    __shared__ float buf[16];
    if (lane == 0) buf[wave] = local;
    __syncthreads();
    if (tid == 0) {
        float a = 0.f;
#pragma unroll
        for (int i = 0; i < 16; ++i) a += buf[i];
        out[0] = a / (float)B;
    }
}

extern "C" void kernel_launch(void* const* d_in, const int* in_sizes, int n_in,
                              void* d_out, int out_size, void* d_ws, size_t ws_size,
                              hipStream_t stream) {
    const float* feats = (const float*)d_in[0];
    const float* mask  = (const float*)d_in[1];
    const int*   tags  = (const int*)d_in[2];
    const float* trans = (const float*)d_in[3];
    float* out = (float*)d_out;

    const int S = 512;              // reference shape
    const int B = in_sizes[1] / S;  // mask is (B,S)
    const int H = S / 2;

    float* zv = (float*)d_ws;
    float* wv = zv + (size_t)B * NTAGS;
    float* gs = wv + (size_t)B * NTAGS;
    int* ez = (int*)(gs + B);
    int* ew = ez + B;

    crf_chains<<<3 * B, 64, 0, stream>>>(feats, mask, tags, trans,
                                         zv, wv, gs, ez, ew, S, H, B);
    crf_combine<<<1, 1024, 0, stream>>>(zv, wv, gs, ez, ew, out, B);
}